// Round 1
// baseline (709.592 us; speedup 1.0000x reference)
//
#include <hip/hip_runtime.h>
#include <hip/hip_bf16.h>

typedef __bf16 bf16_t;
typedef bf16_t bf16x8 __attribute__((ext_vector_type(8)));
typedef float f32x4 __attribute__((ext_vector_type(4)));
typedef unsigned short u16;
typedef unsigned int u32;

#define B_    2
#define S_    2048
#define HID   2048
#define NQKV  3072          // (16 + 2*4) * 128
#define HQ_   16
#define HKV_  4
#define D_    128
#define SCALE_ 0.08838834764831845f   // 128^-0.5

__device__ __forceinline__ u16 f2b(float f) {
    __hip_bfloat16 h = __float2bfloat16(f);
    return *reinterpret_cast<u16*>(&h);
}

// ---------------------------------------------------------------- f32 -> bf16
__global__ __launch_bounds__(256) void cvt_f32_bf16(const float* __restrict__ in,
                                                    u16* __restrict__ out, int n4) {
    int i = blockIdx.x * 256 + threadIdx.x;
    if (i >= n4) return;
    float4 v = reinterpret_cast<const float4*>(in)[i];
    ushort4 o;
    o.x = f2b(v.x); o.y = f2b(v.y); o.z = f2b(v.z); o.w = f2b(v.w);
    reinterpret_cast<ushort4*>(out)[i] = o;
}

// ---------------------------------------------------------------- GEMM (A: MxK, B: NxK row-major i.e. B^T, C: MxN f32)
// m97 structure: 128x128 tile, BK=32, global_load_lds w16, 4 waves of 64x64.
__global__ __launch_bounds__(256) void gemm_bt_bf16(const u16* __restrict__ A,
                                                    const u16* __restrict__ Bm,
                                                    float* __restrict__ C,
                                                    int M, int N, int K) {
    __shared__ u16 As[128 * 32];
    __shared__ u16 Bs[128 * 32];
    const int tid  = threadIdx.x;
    const int lane = tid & 63;
    const int wave = tid >> 6;
    const int wr = wave >> 1, wc = wave & 1;
    const int lrow = lane & 15, lgrp = lane >> 4;
    const int m0 = blockIdx.x * 128;
    const int n0 = blockIdx.y * 128;

    const int c0 = tid, c1 = tid + 256;   // 16B chunks (512 per 8KB tile)
    const u16* aG0 = A  + (size_t)(m0 + (c0 >> 2)) * K + (c0 & 3) * 8;
    const u16* aG1 = A  + (size_t)(m0 + (c1 >> 2)) * K + (c1 & 3) * 8;
    const u16* bG0 = Bm + (size_t)(n0 + (c0 >> 2)) * K + (c0 & 3) * 8;
    const u16* bG1 = Bm + (size_t)(n0 + (c1 >> 2)) * K + (c1 & 3) * 8;

    f32x4 acc[4][4] = {};

    for (int k0 = 0; k0 < K; k0 += 32) {
        __builtin_amdgcn_global_load_lds(
            (const __attribute__((address_space(1))) void*)(aG0 + k0),
            (__attribute__((address_space(3))) void*)(As + c0 * 8), 16, 0, 0);
        __builtin_amdgcn_global_load_lds(
            (const __attribute__((address_space(1))) void*)(aG1 + k0),
            (__attribute__((address_space(3))) void*)(As + c1 * 8), 16, 0, 0);
        __builtin_amdgcn_global_load_lds(
            (const __attribute__((address_space(1))) void*)(bG0 + k0),
            (__attribute__((address_space(3))) void*)(Bs + c0 * 8), 16, 0, 0);
        __builtin_amdgcn_global_load_lds(
            (const __attribute__((address_space(1))) void*)(bG1 + k0),
            (__attribute__((address_space(3))) void*)(Bs + c1 * 8), 16, 0, 0);
        __syncthreads();   // drains vmcnt before reads

        bf16x8 af[4], bfr[4];
        #pragma unroll
        for (int mi = 0; mi < 4; mi++)
            af[mi] = *(const bf16x8*)(As + (wr * 64 + mi * 16 + lrow) * 32 + lgrp * 8);
        #pragma unroll
        for (int ni = 0; ni < 4; ni++)
            bfr[ni] = *(const bf16x8*)(Bs + (wc * 64 + ni * 16 + lrow) * 32 + lgrp * 8);
        #pragma unroll
        for (int mi = 0; mi < 4; mi++)
            #pragma unroll
            for (int ni = 0; ni < 4; ni++)
                acc[mi][ni] = __builtin_amdgcn_mfma_f32_16x16x32_bf16(
                    af[mi], bfr[ni], acc[mi][ni], 0, 0, 0);
        __syncthreads();
    }

    #pragma unroll
    for (int mi = 0; mi < 4; mi++) {
        #pragma unroll
        for (int ni = 0; ni < 4; ni++) {
            #pragma unroll
            for (int i = 0; i < 4; i++) {
                int r = m0 + wr * 64 + mi * 16 + lgrp * 4 + i;
                int c = n0 + wc * 64 + ni * 16 + lrow;
                C[(size_t)r * N + c] = acc[mi][ni][i];
            }
        }
    }
}

// ---------------------------------------------------------------- RoPE (interleaved) + RMSNorm + split/relayout
// out layouts: qb (B,HQ,S,D), kb (B,HKV,S,D), vb (B,HKV,S,D), all bf16
__global__ __launch_bounds__(256) void rope_norm_split(const float* __restrict__ qkv,
                                                       const float* __restrict__ cosb,
                                                       const float* __restrict__ sinb,
                                                       const float* __restrict__ nw,
                                                       u16* __restrict__ qb,
                                                       u16* __restrict__ kb,
                                                       u16* __restrict__ vb) {
    const int row  = blockIdx.x;          // b*S + s
    const int b    = row >> 11;
    const int s    = row & 2047;
    const int wave = threadIdx.x >> 6;
    const int lane = threadIdx.x & 63;
    const float* base = qkv + (size_t)row * NQKV;

    const float c0 = cosb[s * 128 + lane];
    const float c1 = cosb[s * 128 + 64 + lane];
    const float s0 = sinb[s * 128 + lane];
    const float s1 = sinb[s * 128 + 64 + lane];
    const float w0 = nw[2 * lane];
    const float w1 = nw[2 * lane + 1];

    for (int h = wave; h < HQ_ + HKV_; h += 4) {          // 0..15 = q heads, 16..19 = k heads
        float2 x = *(const float2*)(base + h * 128 + 2 * lane);
        float y0 = x.x * c0 - x.y * s0;                   // even slot
        float y1 = x.y * c1 + x.x * s1;                   // odd slot
        float ss = y0 * y0 + y1 * y1;
        #pragma unroll
        for (int off = 32; off; off >>= 1) ss += __shfl_xor(ss, off);
        float r = rsqrtf(ss * (1.0f / 128.0f) + 1e-6f);
        u32 pack = (u32)f2b(y0 * r * w0) | ((u32)f2b(y1 * r * w1) << 16);
        if (h < HQ_)
            *(u32*)(qb + ((size_t)(b * HQ_ + h) * S_ + s) * D_ + 2 * lane) = pack;
        else
            *(u32*)(kb + ((size_t)(b * HKV_ + (h - HQ_)) * S_ + s) * D_ + 2 * lane) = pack;
    }
    {   // v heads: one per wave
        int h = wave;
        float2 x = *(const float2*)(base + (HQ_ + HKV_) * 128 + h * 128 + 2 * lane);
        u32 pack = (u32)f2b(x.x) | ((u32)f2b(x.y) << 16);
        *(u32*)(vb + ((size_t)(b * HKV_ + h) * S_ + s) * D_ + 2 * lane) = pack;
    }
}

// ---------------------------------------------------------------- causal GQA flash attention
// grid (S/64, B*HQ); block 256 = 4 waves, each wave owns 16 q rows. KVBLK=32.
__global__ __launch_bounds__(256) void attn_fwd(const u16* __restrict__ qb,
                                                const u16* __restrict__ kb,
                                                const u16* __restrict__ vb,
                                                u16* __restrict__ attn) {
    __shared__ u16 Vt[128 * 40];        // V^T, padded stride 40 (80B, keeps 16B align)
    __shared__ u16 Pl[4][16 * 40];      // per-wave P tile, padded

    const int qt  = blockIdx.x;
    const int bh  = blockIdx.y;
    const int b   = bh >> 4, hq = bh & 15, hkv = hq >> 2;
    const int wave = threadIdx.x >> 6, lane = threadIdx.x & 63;
    const int lrow = lane & 15, lgrp = lane >> 4;

    const u16* Q  = qb + (size_t)(b * HQ_  + hq ) * S_ * D_;
    const u16* Kp = kb + (size_t)(b * HKV_ + hkv) * S_ * D_;
    const u16* Vp = vb + (size_t)(b * HKV_ + hkv) * S_ * D_;
    const int q0 = qt * 64 + wave * 16;

    bf16x8 qf[4];
    #pragma unroll
    for (int ks = 0; ks < 4; ks++)
        qf[ks] = *(const bf16x8*)(Q + (size_t)(q0 + lrow) * D_ + ks * 32 + lgrp * 8);

    float m_i[4] = {-1e30f, -1e30f, -1e30f, -1e30f};
    float l_i[4] = {0.f, 0.f, 0.f, 0.f};
    f32x4 oacc[8] = {};

    const int ktmax = (qt * 64 + 63) >> 5;
    for (int kt = 0; kt <= ktmax; kt++) {
        const int kv0 = kt * 32;
        __syncthreads();                          // protect Vt readers of prev iter
        for (int idx = threadIdx.x * 2; idx < 32 * 128; idx += 512) {
            int kv = idx >> 7, d = idx & 127;     // d even
            u32 two = *(const u32*)(Vp + (size_t)(kv0 + kv) * D_ + d);
            Vt[d * 40 + kv]       = (u16)two;
            Vt[(d + 1) * 40 + kv] = (u16)(two >> 16);
        }
        __syncthreads();

        // ---- QK^T: 16 q-rows x 32 kv-cols
        f32x4 sc0 = {}, sc1 = {};
        #pragma unroll
        for (int ks = 0; ks < 4; ks++) {
            bf16x8 k0f = *(const bf16x8*)(Kp + (size_t)(kv0      + lrow) * D_ + ks * 32 + lgrp * 8);
            bf16x8 k1f = *(const bf16x8*)(Kp + (size_t)(kv0 + 16 + lrow) * D_ + ks * 32 + lgrp * 8);
            sc0 = __builtin_amdgcn_mfma_f32_16x16x32_bf16(qf[ks], k0f, sc0, 0, 0, 0);
            sc1 = __builtin_amdgcn_mfma_f32_16x16x32_bf16(qf[ks], k1f, sc1, 0, 0, 0);
        }

        // ---- online softmax (row = lgrp*4+i, col = lrow / 16+lrow)
        #pragma unroll
        for (int i = 0; i < 4; i++) {
            int qg = q0 + lgrp * 4 + i;
            float v0 = (kv0 + lrow      <= qg) ? sc0[i] * SCALE_ : -1e30f;
            float v1 = (kv0 + 16 + lrow <= qg) ? sc1[i] * SCALE_ : -1e30f;
            float rm = fmaxf(v0, v1);
            rm = fmaxf(rm, __shfl_xor(rm, 1));
            rm = fmaxf(rm, __shfl_xor(rm, 2));
            rm = fmaxf(rm, __shfl_xor(rm, 4));
            rm = fmaxf(rm, __shfl_xor(rm, 8));
            float mnew  = fmaxf(m_i[i], rm);
            float alpha = __expf(m_i[i] - mnew);
            float p0 = __expf(v0 - mnew);
            float p1 = __expf(v1 - mnew);
            float rs = p0 + p1;
            rs += __shfl_xor(rs, 1);
            rs += __shfl_xor(rs, 2);
            rs += __shfl_xor(rs, 4);
            rs += __shfl_xor(rs, 8);
            l_i[i] = l_i[i] * alpha + rs;
            m_i[i] = mnew;
            #pragma unroll
            for (int dt = 0; dt < 8; dt++) oacc[dt][i] *= alpha;
            int prow = lgrp * 4 + i;
            Pl[wave][prow * 40 + lrow]      = f2b(p0);
            Pl[wave][prow * 40 + 16 + lrow] = f2b(p1);
        }

        // ---- PV: P(16x32) @ V(32x128)
        bf16x8 ap = *(const bf16x8*)(&Pl[wave][lrow * 40 + lgrp * 8]);
        #pragma unroll
        for (int dt = 0; dt < 8; dt++) {
            bf16x8 bv = *(const bf16x8*)(&Vt[(dt * 16 + lrow) * 40 + lgrp * 8]);
            oacc[dt] = __builtin_amdgcn_mfma_f32_16x16x32_bf16(ap, bv, oacc[dt], 0, 0, 0);
        }
    }

    // ---- epilogue: attn (B*S, HQ*D) bf16
    #pragma unroll
    for (int i = 0; i < 4; i++) {
        float inv = 1.0f / l_i[i];
        int qg = q0 + lgrp * 4 + i;
        u16* orow = attn + (size_t)(b * S_ + qg) * (HQ_ * D_) + hq * D_;
        #pragma unroll
        for (int dt = 0; dt < 8; dt++)
            orow[dt * 16 + lrow] = f2b(oacc[dt][i] * inv);
    }
}

// ---------------------------------------------------------------- launcher
extern "C" void kernel_launch(void* const* d_in, const int* in_sizes, int n_in,
                              void* d_out, int out_size, void* d_ws, size_t ws_size,
                              hipStream_t stream) {
    const float* hidden = (const float*)d_in[0];   // (B,S,HID)
    const float* cosb   = (const float*)d_in[1];   // (S,D)
    const float* sinb   = (const float*)d_in[2];   // (S,D)
    const float* qkvw   = (const float*)d_in[3];   // (NQKV,HID)
    const float* nw     = (const float*)d_in[4];   // (D,)
    const float* ow     = (const float*)d_in[5];   // (HID, HQ*D)
    float* out = (float*)d_out;

    const size_t M  = (size_t)B_ * S_;             // 4096
    char* ws = (char*)d_ws;
    size_t off = 0;
    u16*   hb    = (u16*)(ws + off); off += M * HID * 2;                    // 16 MB (reused as attn)
    u16*   wqkvb = (u16*)(ws + off); off += (size_t)NQKV * HID * 2;         // 12 MB
    u16*   wob   = (u16*)(ws + off); off += (size_t)HID * (HQ_ * D_) * 2;   // 8 MB
    float* qkv   = (float*)(ws + off); off += M * NQKV * 4;                 // 48 MB
    u16*   qb2   = (u16*)(ws + off); off += (size_t)B_ * HQ_  * S_ * D_ * 2; // 16 MB
    u16*   kb2   = (u16*)(ws + off); off += (size_t)B_ * HKV_ * S_ * D_ * 2; // 4 MB
    u16*   vb2   = (u16*)(ws + off); off += (size_t)B_ * HKV_ * S_ * D_ * 2; // 4 MB
    u16*   attn  = hb;  // reuse: hb's last read is GEMM1, attn written after

    // 1) conversions
    {
        int n4 = (int)(M * HID / 4);
        cvt_f32_bf16<<<(n4 + 255) / 256, 256, 0, stream>>>(hidden, hb, n4);
    }
    {
        int n4 = NQKV * HID / 4;
        cvt_f32_bf16<<<(n4 + 255) / 256, 256, 0, stream>>>(qkvw, wqkvb, n4);
    }
    {
        int n4 = HID * (HQ_ * D_) / 4;
        cvt_f32_bf16<<<(n4 + 255) / 256, 256, 0, stream>>>(ow, wob, n4);
    }

    // 2) QKV projection: (4096 x 2048) @ (3072 x 2048)^T -> f32
    gemm_bt_bf16<<<dim3(M / 128, NQKV / 128), 256, 0, stream>>>(hb, wqkvb, qkv,
                                                                (int)M, NQKV, HID);

    // 3) RoPE + RMSNorm + relayout
    rope_norm_split<<<(int)M, 256, 0, stream>>>(qkv, cosb, sinb, nw, qb2, kb2, vb2);

    // 4) causal GQA attention
    attn_fwd<<<dim3(S_ / 64, B_ * HQ_), 256, 0, stream>>>(qb2, kb2, vb2, attn);

    // 5) output projection: (4096 x 2048) @ (2048 x 2048)^T -> d_out f32
    gemm_bt_bf16<<<dim3(M / 128, HID / 128), 256, 0, stream>>>(attn, wob, out,
                                                               (int)M, HID, HQ_ * D_);
}

// Round 2
// 333.326 us; speedup vs baseline: 2.1288x; 2.1288x over previous
//
#include <hip/hip_runtime.h>
#include <hip/hip_bf16.h>

typedef __bf16 bf16_t;
typedef bf16_t bf16x8 __attribute__((ext_vector_type(8)));
typedef float f32x4 __attribute__((ext_vector_type(4)));
typedef unsigned short u16;
typedef unsigned int u32;

#define B_    2
#define S_    2048
#define HID   2048
#define NQKV  3072          // (16 + 2*4) * 128
#define HQ_   16
#define HKV_  4
#define D_    128
#define SCALE_ 0.08838834764831845f   // 128^-0.5

__device__ __forceinline__ u16 f2b(float f) {
    __hip_bfloat16 h = __float2bfloat16(f);
    return *reinterpret_cast<u16*>(&h);
}

// ---------------------------------------------------------------- f32 -> bf16
__global__ __launch_bounds__(256) void cvt_f32_bf16(const float* __restrict__ in,
                                                    u16* __restrict__ out, int n4) {
    int i = blockIdx.x * 256 + threadIdx.x;
    if (i >= n4) return;
    float4 v = reinterpret_cast<const float4*>(in)[i];
    ushort4 o;
    o.x = f2b(v.x); o.y = f2b(v.y); o.z = f2b(v.z); o.w = f2b(v.w);
    reinterpret_cast<ushort4*>(out)[i] = o;
}

// ---------------------------------------------------------------- GEMM (A: MxK, B: NxK row-major i.e. B^T, C: MxN f32)
__global__ __launch_bounds__(256) void gemm_bt_bf16(const u16* __restrict__ A,
                                                    const u16* __restrict__ Bm,
                                                    float* __restrict__ C,
                                                    int M, int N, int K) {
    __shared__ u16 As[128 * 32];
    __shared__ u16 Bs[128 * 32];
    const int tid  = threadIdx.x;
    const int lane = tid & 63;
    const int wave = tid >> 6;
    const int wr = wave >> 1, wc = wave & 1;
    const int lrow = lane & 15, lgrp = lane >> 4;
    const int m0 = blockIdx.x * 128;
    const int n0 = blockIdx.y * 128;

    const int c0 = tid, c1 = tid + 256;
    const u16* aG0 = A  + (size_t)(m0 + (c0 >> 2)) * K + (c0 & 3) * 8;
    const u16* aG1 = A  + (size_t)(m0 + (c1 >> 2)) * K + (c1 & 3) * 8;
    const u16* bG0 = Bm + (size_t)(n0 + (c0 >> 2)) * K + (c0 & 3) * 8;
    const u16* bG1 = Bm + (size_t)(n0 + (c1 >> 2)) * K + (c1 & 3) * 8;

    f32x4 acc[4][4] = {};

    for (int k0 = 0; k0 < K; k0 += 32) {
        __builtin_amdgcn_global_load_lds(
            (const __attribute__((address_space(1))) void*)(aG0 + k0),
            (__attribute__((address_space(3))) void*)(As + c0 * 8), 16, 0, 0);
        __builtin_amdgcn_global_load_lds(
            (const __attribute__((address_space(1))) void*)(aG1 + k0),
            (__attribute__((address_space(3))) void*)(As + c1 * 8), 16, 0, 0);
        __builtin_amdgcn_global_load_lds(
            (const __attribute__((address_space(1))) void*)(bG0 + k0),
            (__attribute__((address_space(3))) void*)(Bs + c0 * 8), 16, 0, 0);
        __builtin_amdgcn_global_load_lds(
            (const __attribute__((address_space(1))) void*)(bG1 + k0),
            (__attribute__((address_space(3))) void*)(Bs + c1 * 8), 16, 0, 0);
        __syncthreads();

        bf16x8 af[4], bfr[4];
        #pragma unroll
        for (int mi = 0; mi < 4; mi++)
            af[mi] = *(const bf16x8*)(As + (wr * 64 + mi * 16 + lrow) * 32 + lgrp * 8);
        #pragma unroll
        for (int ni = 0; ni < 4; ni++)
            bfr[ni] = *(const bf16x8*)(Bs + (wc * 64 + ni * 16 + lrow) * 32 + lgrp * 8);
        #pragma unroll
        for (int mi = 0; mi < 4; mi++)
            #pragma unroll
            for (int ni = 0; ni < 4; ni++)
                acc[mi][ni] = __builtin_amdgcn_mfma_f32_16x16x32_bf16(
                    af[mi], bfr[ni], acc[mi][ni], 0, 0, 0);
        __syncthreads();
    }

    #pragma unroll
    for (int mi = 0; mi < 4; mi++) {
        #pragma unroll
        for (int ni = 0; ni < 4; ni++) {
            #pragma unroll
            for (int i = 0; i < 4; i++) {
                int r = m0 + wr * 64 + mi * 16 + lgrp * 4 + i;
                int c = n0 + wc * 64 + ni * 16 + lrow;
                C[(size_t)r * N + c] = acc[mi][ni][i];
            }
        }
    }
}

// ---------------------------------------------------------------- RoPE (interleaved) + RMSNorm + split/relayout
__global__ __launch_bounds__(256) void rope_norm_split(const float* __restrict__ qkv,
                                                       const float* __restrict__ cosb,
                                                       const float* __restrict__ sinb,
                                                       const float* __restrict__ nw,
                                                       u16* __restrict__ qb,
                                                       u16* __restrict__ kb,
                                                       u16* __restrict__ vb) {
    const int row  = blockIdx.x;          // b*S + s
    const int b    = row >> 11;
    const int s    = row & 2047;
    const int wave = threadIdx.x >> 6;
    const int lane = threadIdx.x & 63;
    const float* base = qkv + (size_t)row * NQKV;

    const float c0 = cosb[s * 128 + lane];
    const float c1 = cosb[s * 128 + 64 + lane];
    const float s0 = sinb[s * 128 + lane];
    const float s1 = sinb[s * 128 + 64 + lane];
    const float w0 = nw[2 * lane];
    const float w1 = nw[2 * lane + 1];

    for (int h = wave; h < HQ_ + HKV_; h += 4) {
        float2 x = *(const float2*)(base + h * 128 + 2 * lane);
        float y0 = x.x * c0 - x.y * s0;
        float y1 = x.y * c1 + x.x * s1;
        float ss = y0 * y0 + y1 * y1;
        #pragma unroll
        for (int off = 32; off; off >>= 1) ss += __shfl_xor(ss, off);
        float r = rsqrtf(ss * (1.0f / 128.0f) + 1e-6f);
        u32 pack = (u32)f2b(y0 * r * w0) | ((u32)f2b(y1 * r * w1) << 16);
        if (h < HQ_)
            *(u32*)(qb + ((size_t)(b * HQ_ + h) * S_ + s) * D_ + 2 * lane) = pack;
        else
            *(u32*)(kb + ((size_t)(b * HKV_ + (h - HQ_)) * S_ + s) * D_ + 2 * lane) = pack;
    }
    {
        int h = wave;
        float2 x = *(const float2*)(base + (HQ_ + HKV_) * 128 + h * 128 + 2 * lane);
        u32 pack = (u32)f2b(x.x) | ((u32)f2b(x.y) << 16);
        *(u32*)(vb + ((size_t)(b * HKV_ + h) * S_ + s) * D_ + 2 * lane) = pack;
    }
}

// ---------------------------------------------------------------- V transpose: (B,HKV,S,D) -> (B,HKV,D,S)
__global__ __launch_bounds__(256) void transpose_v(const u16* __restrict__ vb,
                                                   u16* __restrict__ vtb) {
    __shared__ u16 t[64][72];           // 72-elem stride: phase-1 b128-aligned, phase-2 conflict-free
    const int s0 = blockIdx.x * 64, d0 = blockIdx.y * 64, bh = blockIdx.z;
    const u16* src = vb  + (size_t)bh * S_ * D_;
    u16*       dst = vtb + (size_t)bh * D_ * S_;
    const int tid = threadIdx.x;

    {   // load 64 s-rows x 64 d-cols, coalesced
        int r = tid >> 3, c8 = (tid & 7) * 8;
        #pragma unroll
        for (int p = 0; p < 2; p++) {
            int rr = r + p * 32;
            *(uint4*)&t[rr][c8] = *(const uint4*)(src + (size_t)(s0 + rr) * D_ + d0 + c8);
        }
    }
    __syncthreads();
    {   // write transposed: dd = tid&63 (whole wave spreads banks), ss8 per wave
        int dd = tid & 63;
        int sb = (tid >> 6) * 8;
        #pragma unroll
        for (int p = 0; p < 2; p++) {
            int ss8 = sb + p * 32;
            union { u16 u[8]; uint4 v; } pk;
            #pragma unroll
            for (int j = 0; j < 8; j++) pk.u[j] = t[ss8 + j][dd];
            *(uint4*)(dst + (size_t)(d0 + dd) * S_ + s0 + ss8) = pk.v;
        }
    }
}

// ---------------------------------------------------------------- causal GQA flash attention v2
// grid (32 qtiles reversed, B*HQ); 4 waves; QBLK=64 (16 q/wave), KVBLK=64.
// K [64][128] and V^T [128][64] double-buffered in LDS, XOR-swizzled, staged
// via global_load_lds w16 with pre-swizzled source; counted vmcnt pipeline.
__global__ __launch_bounds__(256) void attn_fwd2(const u16* __restrict__ qb,
                                                 const u16* __restrict__ kb,
                                                 const u16* __restrict__ vtb,
                                                 u16* __restrict__ attn) {
    __shared__ u16 Ks[2][64 * 128];     // 16KB x2
    __shared__ u16 Vs[2][128 * 64];     // 16KB x2
    __shared__ u16 Pl[4][16 * 72];      // per-wave P tile, stride 72 elems (144B, 16B-aligned)

    const int qt  = 31 - blockIdx.x;    // longest blocks dispatch first
    const int bh  = blockIdx.y;
    const int b   = bh >> 4, hq = bh & 15, hkv = hq >> 2;
    const int tid = threadIdx.x;
    const int wave = tid >> 6, lane = tid & 63;
    const int lrow = lane & 15, lgrp = lane >> 4;
    const int kxor = (lrow & 7) << 4;

    const u16* Q  = qb  + (size_t)(b * HQ_  + hq ) * S_ * D_;
    const u16* Kp = kb  + (size_t)(b * HKV_ + hkv) * S_ * D_;
    const u16* Vt = vtb + (size_t)(b * HKV_ + hkv) * D_ * S_;
    const int q0 = qt * 64 + wave * 16;

    // staging chunk geometry (1024 x 16B chunks per tile, 4 per thread)
    int kSrc[4], vSrc[4], cLds[4];
    #pragma unroll
    for (int p = 0; p < 4; p++) {
        int c = tid + p * 256;
        int kr = c >> 4, kc = ((c & 15) * 16) ^ ((kr & 7) << 4);   // bytes, src pre-swizzle
        kSrc[p] = kr * D_ + (kc >> 1);
        int vr = c >> 3, vc = ((c & 7) * 16) ^ ((vr & 7) << 4);
        vSrc[p] = vr * S_ + (vc >> 1);
        cLds[p] = c * 16;
    }

    auto STAGE = [&](int buf, int kv0s) {
        const u16* kbase = Kp + (size_t)kv0s * D_;
        const u16* vbase = Vt + kv0s;
        #pragma unroll
        for (int p = 0; p < 4; p++)
            __builtin_amdgcn_global_load_lds(
                (const __attribute__((address_space(1))) void*)(kbase + kSrc[p]),
                (__attribute__((address_space(3))) void*)((char*)Ks[buf] + cLds[p]), 16, 0, 0);
        #pragma unroll
        for (int p = 0; p < 4; p++)
            __builtin_amdgcn_global_load_lds(
                (const __attribute__((address_space(1))) void*)(vbase + vSrc[p]),
                (__attribute__((address_space(3))) void*)((char*)Vs[buf] + cLds[p]), 16, 0, 0);
    };

    bf16x8 qf[4];
    #pragma unroll
    for (int ks = 0; ks < 4; ks++)
        qf[ks] = *(const bf16x8*)(Q + (size_t)(q0 + lrow) * D_ + ks * 32 + lgrp * 8);

    float m_i[4] = {-1e30f, -1e30f, -1e30f, -1e30f};
    float l_i[4] = {0.f, 0.f, 0.f, 0.f};
    f32x4 oacc[8] = {};

    const int nkt = qt + 1;
    STAGE(0, 0);

    for (int kt = 0; kt < nkt; kt++) {
        const int cur = kt & 1;
        const int kv0 = kt * 64;
        if (kt + 1 < nkt) {
            STAGE(cur ^ 1, kv0 + 64);
            asm volatile("s_waitcnt vmcnt(8)" ::: "memory");   // current tile landed, next in flight
        } else {
            asm volatile("s_waitcnt vmcnt(0)" ::: "memory");
        }
        __builtin_amdgcn_s_barrier();

        // ---- QK^T: 16 q-rows x 64 kv-cols per wave
        const char* ksb = (const char*)Ks[cur];
        f32x4 sc[4] = {};
        #pragma unroll
        for (int sub = 0; sub < 4; sub++) {
            const char* rowb = ksb + (sub * 16 + lrow) * 256;
            #pragma unroll
            for (int ks = 0; ks < 4; ks++) {
                bf16x8 kf = *(const bf16x8*)(rowb + ((ks * 64 + lgrp * 16) ^ kxor));
                sc[sub] = __builtin_amdgcn_mfma_f32_16x16x32_bf16(qf[ks], kf, sc[sub], 0, 0, 0);
            }
        }

        // ---- online softmax (row = lgrp*4+i, cols = sub*16+lrow)
        const bool needMask = (kt == nkt - 1);   // only the diagonal tile
        #pragma unroll
        for (int i = 0; i < 4; i++) {
            float v0 = sc[0][i] * SCALE_, v1 = sc[1][i] * SCALE_;
            float v2 = sc[2][i] * SCALE_, v3 = sc[3][i] * SCALE_;
            if (needMask) {
                int qg = q0 + lgrp * 4 + i;
                int kvb = kv0 + lrow;
                v0 = (kvb      <= qg) ? v0 : -1e30f;
                v1 = (kvb + 16 <= qg) ? v1 : -1e30f;
                v2 = (kvb + 32 <= qg) ? v2 : -1e30f;
                v3 = (kvb + 48 <= qg) ? v3 : -1e30f;
            }
            float rm = fmaxf(fmaxf(v0, v1), fmaxf(v2, v3));
            rm = fmaxf(rm, __shfl_xor(rm, 1));
            rm = fmaxf(rm, __shfl_xor(rm, 2));
            rm = fmaxf(rm, __shfl_xor(rm, 4));
            rm = fmaxf(rm, __shfl_xor(rm, 8));
            float mnew  = fmaxf(m_i[i], rm);
            float alpha = __expf(m_i[i] - mnew);
            float p0 = __expf(v0 - mnew), p1 = __expf(v1 - mnew);
            float p2 = __expf(v2 - mnew), p3 = __expf(v3 - mnew);
            float rs = (p0 + p1) + (p2 + p3);
            rs += __shfl_xor(rs, 1);
            rs += __shfl_xor(rs, 2);
            rs += __shfl_xor(rs, 4);
            rs += __shfl_xor(rs, 8);
            l_i[i] = l_i[i] * alpha + rs;
            m_i[i] = mnew;
            #pragma unroll
            for (int dt = 0; dt < 8; dt++) oacc[dt][i] *= alpha;
            int prow = lgrp * 4 + i;
            Pl[wave][prow * 72 + lrow]      = f2b(p0);
            Pl[wave][prow * 72 + 16 + lrow] = f2b(p1);
            Pl[wave][prow * 72 + 32 + lrow] = f2b(p2);
            Pl[wave][prow * 72 + 48 + lrow] = f2b(p3);
        }

        // ---- PV: P(16x64) @ V(64x128), B-frags from swizzled V^T LDS
        const char* vsb = (const char*)Vs[cur];
        const char* plb = (const char*)Pl[wave] + lrow * 144 + lgrp * 16;
        bf16x8 ap0 = *(const bf16x8*)(plb);
        bf16x8 ap1 = *(const bf16x8*)(plb + 64);
        #pragma unroll
        for (int dt = 0; dt < 8; dt++) {
            const char* vrow = vsb + (dt * 16 + lrow) * 128;
            bf16x8 bv0 = *(const bf16x8*)(vrow + ((lgrp * 16) ^ kxor));
            bf16x8 bv1 = *(const bf16x8*)(vrow + ((64 + lgrp * 16) ^ kxor));
            oacc[dt] = __builtin_amdgcn_mfma_f32_16x16x32_bf16(ap0, bv0, oacc[dt], 0, 0, 0);
            oacc[dt] = __builtin_amdgcn_mfma_f32_16x16x32_bf16(ap1, bv1, oacc[dt], 0, 0, 0);
        }
        __builtin_amdgcn_s_barrier();   // all reads of buf[cur] done before it is restaged
    }

    // ---- epilogue
    #pragma unroll
    for (int i = 0; i < 4; i++) {
        float inv = 1.0f / l_i[i];
        int qg = q0 + lgrp * 4 + i;
        u16* orow = attn + (size_t)(b * S_ + qg) * (HQ_ * D_) + hq * D_;
        #pragma unroll
        for (int dt = 0; dt < 8; dt++)
            orow[dt * 16 + lrow] = f2b(oacc[dt][i] * inv);
    }
}

// ---------------------------------------------------------------- launcher
extern "C" void kernel_launch(void* const* d_in, const int* in_sizes, int n_in,
                              void* d_out, int out_size, void* d_ws, size_t ws_size,
                              hipStream_t stream) {
    const float* hidden = (const float*)d_in[0];
    const float* cosb   = (const float*)d_in[1];
    const float* sinb   = (const float*)d_in[2];
    const float* qkvw   = (const float*)d_in[3];
    const float* nw     = (const float*)d_in[4];
    const float* ow     = (const float*)d_in[5];
    float* out = (float*)d_out;

    const size_t M  = (size_t)B_ * S_;             // 4096
    char* ws = (char*)d_ws;
    size_t off = 0;
    u16*   hb    = (u16*)(ws + off); off += M * HID * 2;                     // 16 MB (reused as attn)
    u16*   wqkvb = (u16*)(ws + off); off += (size_t)NQKV * HID * 2;          // 12 MB
    u16*   wob   = (u16*)(ws + off); off += (size_t)HID * (HQ_ * D_) * 2;    // 8 MB
    float* qkv   = (float*)(ws + off); off += M * NQKV * 4;                  // 48 MB
    u16*   qb2   = (u16*)(ws + off); off += (size_t)B_ * HQ_  * S_ * D_ * 2; // 16 MB
    u16*   kb2   = (u16*)(ws + off); off += (size_t)B_ * HKV_ * S_ * D_ * 2; // 4 MB
    u16*   vb2   = (u16*)(ws + off); off += (size_t)B_ * HKV_ * S_ * D_ * 2; // 4 MB
    u16*   vtb   = (u16*)(ws + off); off += (size_t)B_ * HKV_ * S_ * D_ * 2; // 4 MB
    u16*   attn  = hb;

    {
        int n4 = (int)(M * HID / 4);
        cvt_f32_bf16<<<(n4 + 255) / 256, 256, 0, stream>>>(hidden, hb, n4);
    }
    {
        int n4 = NQKV * HID / 4;
        cvt_f32_bf16<<<(n4 + 255) / 256, 256, 0, stream>>>(qkvw, wqkvb, n4);
    }
    {
        int n4 = HID * (HQ_ * D_) / 4;
        cvt_f32_bf16<<<(n4 + 255) / 256, 256, 0, stream>>>(ow, wob, n4);
    }

    gemm_bt_bf16<<<dim3(M / 128, NQKV / 128), 256, 0, stream>>>(hb, wqkvb, qkv,
                                                                (int)M, NQKV, HID);

    rope_norm_split<<<(int)M, 256, 0, stream>>>(qkv, cosb, sinb, nw, qb2, kb2, vb2);

    transpose_v<<<dim3(S_ / 64, D_ / 64, B_ * HKV_), 256, 0, stream>>>(vb2, vtb);

    attn_fwd2<<<dim3(32, B_ * HQ_), 256, 0, stream>>>(qb2, kb2, vtb, attn);

    gemm_bt_bf16<<<dim3(M / 128, HID / 128), 256, 0, stream>>>(attn, wob, out,
                                                               (int)M, HID, HQ_ * D_);
}

// Round 3
// 241.265 us; speedup vs baseline: 2.9411x; 1.3816x over previous
//
#include <hip/hip_runtime.h>
#include <hip/hip_bf16.h>

typedef __bf16 bf16_t;
typedef bf16_t bf16x8 __attribute__((ext_vector_type(8)));
typedef float f32x4 __attribute__((ext_vector_type(4)));
typedef float f32x16 __attribute__((ext_vector_type(16)));
typedef unsigned short u16;
typedef unsigned int u32;

#define B_    2
#define S_    2048
#define HID   2048
#define NQKV  3072          // (16 + 2*4) * 128
#define HQ_   16
#define HKV_  4
#define D_    128
// D^-0.5 * log2(e): folded into Q so softmax runs in exp2 domain
#define QSCALE_ 0.12751879526600565f

__device__ __forceinline__ u16 f2b(float f) {
    __hip_bfloat16 h = __float2bfloat16(f);
    return *reinterpret_cast<u16*>(&h);
}

// ---------------------------------------------------------------- f32 -> bf16
__global__ __launch_bounds__(256) void cvt_f32_bf16(const float* __restrict__ in,
                                                    u16* __restrict__ out, int n4) {
    int i = blockIdx.x * 256 + threadIdx.x;
    if (i >= n4) return;
    float4 v = reinterpret_cast<const float4*>(in)[i];
    ushort4 o;
    o.x = f2b(v.x); o.y = f2b(v.y); o.z = f2b(v.z); o.w = f2b(v.w);
    reinterpret_cast<ushort4*>(out)[i] = o;
}

// ---------------------------------------------------------------- GEMM (A: MxK, B: NxK row-major i.e. B^T, C: MxN f32)
__global__ __launch_bounds__(256) void gemm_bt_bf16(const u16* __restrict__ A,
                                                    const u16* __restrict__ Bm,
                                                    float* __restrict__ C,
                                                    int M, int N, int K) {
    __shared__ u16 As[128 * 32];
    __shared__ u16 Bs[128 * 32];
    const int tid  = threadIdx.x;
    const int lane = tid & 63;
    const int wave = tid >> 6;
    const int wr = wave >> 1, wc = wave & 1;
    const int lrow = lane & 15, lgrp = lane >> 4;
    const int m0 = blockIdx.x * 128;
    const int n0 = blockIdx.y * 128;

    const int c0 = tid, c1 = tid + 256;
    const u16* aG0 = A  + (size_t)(m0 + (c0 >> 2)) * K + (c0 & 3) * 8;
    const u16* aG1 = A  + (size_t)(m0 + (c1 >> 2)) * K + (c1 & 3) * 8;
    const u16* bG0 = Bm + (size_t)(n0 + (c0 >> 2)) * K + (c0 & 3) * 8;
    const u16* bG1 = Bm + (size_t)(n0 + (c1 >> 2)) * K + (c1 & 3) * 8;

    f32x4 acc[4][4] = {};

    for (int k0 = 0; k0 < K; k0 += 32) {
        __builtin_amdgcn_global_load_lds(
            (const __attribute__((address_space(1))) void*)(aG0 + k0),
            (__attribute__((address_space(3))) void*)(As + c0 * 8), 16, 0, 0);
        __builtin_amdgcn_global_load_lds(
            (const __attribute__((address_space(1))) void*)(aG1 + k0),
            (__attribute__((address_space(3))) void*)(As + c1 * 8), 16, 0, 0);
        __builtin_amdgcn_global_load_lds(
            (const __attribute__((address_space(1))) void*)(bG0 + k0),
            (__attribute__((address_space(3))) void*)(Bs + c0 * 8), 16, 0, 0);
        __builtin_amdgcn_global_load_lds(
            (const __attribute__((address_space(1))) void*)(bG1 + k0),
            (__attribute__((address_space(3))) void*)(Bs + c1 * 8), 16, 0, 0);
        __syncthreads();

        bf16x8 af[4], bfr[4];
        #pragma unroll
        for (int mi = 0; mi < 4; mi++)
            af[mi] = *(const bf16x8*)(As + (wr * 64 + mi * 16 + lrow) * 32 + lgrp * 8);
        #pragma unroll
        for (int ni = 0; ni < 4; ni++)
            bfr[ni] = *(const bf16x8*)(Bs + (wc * 64 + ni * 16 + lrow) * 32 + lgrp * 8);
        #pragma unroll
        for (int mi = 0; mi < 4; mi++)
            #pragma unroll
            for (int ni = 0; ni < 4; ni++)
                acc[mi][ni] = __builtin_amdgcn_mfma_f32_16x16x32_bf16(
                    af[mi], bfr[ni], acc[mi][ni], 0, 0, 0);
        __syncthreads();
    }

    #pragma unroll
    for (int mi = 0; mi < 4; mi++) {
        #pragma unroll
        for (int ni = 0; ni < 4; ni++) {
            #pragma unroll
            for (int i = 0; i < 4; i++) {
                int r = m0 + wr * 64 + mi * 16 + lgrp * 4 + i;
                int c = n0 + wc * 64 + ni * 16 + lrow;
                C[(size_t)r * N + c] = acc[mi][ni][i];
            }
        }
    }
}

// ---------------------------------------------------------------- RoPE (interleaved) + RMSNorm + split/relayout
// Q additionally pre-scaled by D^-0.5 * log2(e) (softmax runs in exp2 domain).
__global__ __launch_bounds__(256) void rope_norm_split(const float* __restrict__ qkv,
                                                       const float* __restrict__ cosb,
                                                       const float* __restrict__ sinb,
                                                       const float* __restrict__ nw,
                                                       u16* __restrict__ qb,
                                                       u16* __restrict__ kb,
                                                       u16* __restrict__ vb) {
    const int row  = blockIdx.x;          // b*S + s
    const int b    = row >> 11;
    const int s    = row & 2047;
    const int wave = threadIdx.x >> 6;
    const int lane = threadIdx.x & 63;
    const float* base = qkv + (size_t)row * NQKV;

    const float c0 = cosb[s * 128 + lane];
    const float c1 = cosb[s * 128 + 64 + lane];
    const float s0 = sinb[s * 128 + lane];
    const float s1 = sinb[s * 128 + 64 + lane];
    const float w0 = nw[2 * lane];
    const float w1 = nw[2 * lane + 1];

    for (int h = wave; h < HQ_ + HKV_; h += 4) {
        float2 x = *(const float2*)(base + h * 128 + 2 * lane);
        float y0 = x.x * c0 - x.y * s0;
        float y1 = x.y * c1 + x.x * s1;
        float ss = y0 * y0 + y1 * y1;
        #pragma unroll
        for (int off = 32; off; off >>= 1) ss += __shfl_xor(ss, off);
        float r = rsqrtf(ss * (1.0f / 128.0f) + 1e-6f);
        float o0 = y0 * r * w0, o1 = y1 * r * w1;
        if (h < HQ_) {
            u32 pack = (u32)f2b(o0 * QSCALE_) | ((u32)f2b(o1 * QSCALE_) << 16);
            *(u32*)(qb + ((size_t)(b * HQ_ + h) * S_ + s) * D_ + 2 * lane) = pack;
        } else {
            u32 pack = (u32)f2b(o0) | ((u32)f2b(o1) << 16);
            *(u32*)(kb + ((size_t)(b * HKV_ + (h - HQ_)) * S_ + s) * D_ + 2 * lane) = pack;
        }
    }
    {
        int h = wave;
        float2 x = *(const float2*)(base + (HQ_ + HKV_) * 128 + h * 128 + 2 * lane);
        u32 pack = (u32)f2b(x.x) | ((u32)f2b(x.y) << 16);
        *(u32*)(vb + ((size_t)(b * HKV_ + h) * S_ + s) * D_ + 2 * lane) = pack;
    }
}

// ---------------------------------------------------------------- V transpose: (B,HKV,S,D) -> (B,HKV,D,S)
__global__ __launch_bounds__(256) void transpose_v(const u16* __restrict__ vb,
                                                   u16* __restrict__ vtb) {
    __shared__ u16 t[64][72];
    const int s0 = blockIdx.x * 64, d0 = blockIdx.y * 64, bh = blockIdx.z;
    const u16* src = vb  + (size_t)bh * S_ * D_;
    u16*       dst = vtb + (size_t)bh * D_ * S_;
    const int tid = threadIdx.x;

    {
        int r = tid >> 3, c8 = (tid & 7) * 8;
        #pragma unroll
        for (int p = 0; p < 2; p++) {
            int rr = r + p * 32;
            *(uint4*)&t[rr][c8] = *(const uint4*)(src + (size_t)(s0 + rr) * D_ + d0 + c8);
        }
    }
    __syncthreads();
    {
        int dd = tid & 63;
        int sb = (tid >> 6) * 8;
        #pragma unroll
        for (int p = 0; p < 2; p++) {
            int ss8 = sb + p * 32;
            union { u16 u[8]; uint4 v; } pk;
            #pragma unroll
            for (int j = 0; j < 8; j++) pk.u[j] = t[ss8 + j][dd];
            *(uint4*)(dst + (size_t)(d0 + dd) * S_ + s0 + ss8) = pk.v;
        }
    }
}

// ---------------------------------------------------------------- causal GQA flash attention v3
// Swapped-QK^T structure (m214-style): 4 waves x 32 q-rows (QBLK=128), KVBLK=64,
// mfma_32x32x16. Each lane owns one q-row: softmax fully in-lane (+2 shfl/tile).
// PV computed as mfma(V^T, P) so O stays q=lane-local. K,V^T in XOR-swizzled
// double-buffered LDS via global_load_lds(16); counted vmcnt pipeline.
__global__ __launch_bounds__(256, 2) void attn_fwd3(const u16* __restrict__ qb,
                                                    const u16* __restrict__ kb,
                                                    const u16* __restrict__ vtb,
                                                    u16* __restrict__ attn) {
    __shared__ __align__(16) u16 Ks[2][64 * 128];   // 32KB (reused as O bounce)
    __shared__ __align__(16) u16 Vs[2][128 * 64];   // 32KB

    const int bh  = blockIdx.y;
    // depth-complementary pairing: blocks id and id+256 land on the same CU;
    // give them qt and 15-qt so per-CU causal work is ~constant.
    const int qt  = (bh < 16) ? (15 - (int)blockIdx.x) : (int)blockIdx.x;
    const int b   = bh >> 4, hq = bh & 15, hkv = hq >> 2;
    const int tid = threadIdx.x;
    const int wave = tid >> 6, lane = tid & 63;
    const int l31 = lane & 31, hi = lane >> 5;
    const int swz = (l31 & 7) << 4;

    const u16* Q  = qb  + (size_t)(b * HQ_  + hq ) * S_ * D_;
    const u16* Kp = kb  + (size_t)(b * HKV_ + hkv) * S_ * D_;
    const u16* Vt = vtb + (size_t)(b * HKV_ + hkv) * D_ * S_;
    const int q0w = qt * 128 + wave * 32;
    const int qg  = q0w + l31;            // this lane's q row

    // staging geometry: 1024 x 16B chunks per tile, 4 per thread, src pre-swizzled
    int kSrc[4], vSrc[4], cLds[4];
    #pragma unroll
    for (int p = 0; p < 4; p++) {
        int c = tid + p * 256;
        int kr = c >> 4, kc = ((c & 15) * 16) ^ ((kr & 7) << 4);
        kSrc[p] = kr * D_ + (kc >> 1);
        int vr = c >> 3, vc = ((c & 7) * 16) ^ ((vr & 7) << 4);
        vSrc[p] = vr * S_ + (vc >> 1);
        cLds[p] = c * 16;
    }

    auto STAGE = [&](int buf, int kv0s) {
        const u16* kbase = Kp + (size_t)kv0s * D_;
        const u16* vbase = Vt + kv0s;
        #pragma unroll
        for (int p = 0; p < 4; p++)
            __builtin_amdgcn_global_load_lds(
                (const __attribute__((address_space(1))) void*)(kbase + kSrc[p]),
                (__attribute__((address_space(3))) void*)((char*)Ks[buf] + cLds[p]), 16, 0, 0);
        #pragma unroll
        for (int p = 0; p < 4; p++)
            __builtin_amdgcn_global_load_lds(
                (const __attribute__((address_space(1))) void*)(vbase + vSrc[p]),
                (__attribute__((address_space(3))) void*)((char*)Vs[buf] + cLds[p]), 16, 0, 0);
    };

    // Q fragments: B-operand of QK^T. lane reads its own q row, d = ds*16 + hi*8 + j
    bf16x8 qf[8];
    #pragma unroll
    for (int ds = 0; ds < 8; ds++)
        qf[ds] = *(const bf16x8*)(Q + (size_t)qg * D_ + ds * 16 + hi * 8);

    float m_run = -1e30f, l_run = 0.f;
    f32x16 oacc[4] = {};

    const int nkt = 2 * qt + 2;
    STAGE(0, 0);

    for (int kt = 0; kt < nkt; kt++) {
        const int cur = kt & 1;
        const int kv0 = kt * 64;
        if (kt + 1 < nkt) {
            STAGE(cur ^ 1, kv0 + 64);
            asm volatile("s_waitcnt vmcnt(8)" ::: "memory");
        } else {
            asm volatile("s_waitcnt vmcnt(0)" ::: "memory");
        }
        __builtin_amdgcn_s_barrier();

        // ---- QK^T swapped: sc[blk] = K(32x128) * Q^T -> S[kv][q], q = l31
        const char* ksb = (const char*)Ks[cur];
        f32x16 sc[2] = {};
        __builtin_amdgcn_s_setprio(1);
        #pragma unroll
        for (int blk = 0; blk < 2; blk++) {
            const char* rowb = ksb + (blk * 32 + l31) * 256;
            #pragma unroll
            for (int ds = 0; ds < 8; ds++) {
                bf16x8 kf = *(const bf16x8*)(rowb + ((ds * 32 + hi * 16) ^ swz));
                sc[blk] = __builtin_amdgcn_mfma_f32_32x32x16_bf16(kf, qf[ds], sc[blk], 0, 0, 0);
            }
        }
        __builtin_amdgcn_s_setprio(0);

        // ---- mask (diagonal tiles only); kv of reg r = kv0+blk*32+(r&3)+8*(r>>2)+4*hi
        if (kv0 + 63 > q0w) {
            #pragma unroll
            for (int blk = 0; blk < 2; blk++)
                #pragma unroll
                for (int r = 0; r < 16; r++) {
                    int kvg = kv0 + blk * 32 + (r & 3) + 8 * (r >> 2) + 4 * hi;
                    if (kvg > qg) sc[blk][r] = -1e30f;
                }
        }

        // ---- in-lane row max (tree) + cross-half combine
        float t16[16];
        #pragma unroll
        for (int r = 0; r < 16; r++) t16[r] = fmaxf(sc[0][r], sc[1][r]);
        #pragma unroll
        for (int r = 0; r < 8; r++) t16[r] = fmaxf(t16[r], t16[r + 8]);
        #pragma unroll
        for (int r = 0; r < 4; r++) t16[r] = fmaxf(t16[r], t16[r + 4]);
        float mt = fmaxf(fmaxf(t16[0], t16[1]), fmaxf(t16[2], t16[3]));
        mt = fmaxf(mt, __shfl_xor(mt, 32));

        // ---- defer-max (T13): skip rescale if growth small (P bounded by 2^8)
        bool noDefer = !__all(mt <= m_run + 8.0f);
        float mnew = m_run;
        if (noDefer) {
            mnew = fmaxf(m_run, mt);
            float alpha = __builtin_amdgcn_exp2f(m_run - mnew);
            l_run *= alpha;
            #pragma unroll
            for (int d4 = 0; d4 < 4; d4++)
                #pragma unroll
                for (int r = 0; r < 16; r++) oacc[d4][r] *= alpha;
            m_run = mnew;
        }

        // ---- p = exp2(s - m), pack kv-consecutive pairs to bf16x2 words
        float la = 0.f;
        u32 pk0[8], pk1[8];
        #pragma unroll
        for (int g = 0; g < 4; g++)
            #pragma unroll
            for (int e = 0; e < 2; e++) {
                float a0 = __builtin_amdgcn_exp2f(sc[0][g * 4 + 2 * e]     - mnew);
                float b0 = __builtin_amdgcn_exp2f(sc[0][g * 4 + 2 * e + 1] - mnew);
                float a1 = __builtin_amdgcn_exp2f(sc[1][g * 4 + 2 * e]     - mnew);
                float b1 = __builtin_amdgcn_exp2f(sc[1][g * 4 + 2 * e + 1] - mnew);
                la += (a0 + b0) + (a1 + b1);
                pk0[g * 2 + e] = (u32)f2b(a0) | ((u32)f2b(b0) << 16);
                pk1[g * 2 + e] = (u32)f2b(a1) | ((u32)f2b(b1) << 16);
            }
        la += __shfl_xor(la, 32);
        l_run += la;

        // ---- exchange halves: partner (lane^32) holds the complementary kv quads
        u32 qk0[8], qk1[8];
        #pragma unroll
        for (int i = 0; i < 8; i++) {
            qk0[i] = __shfl_xor(pk0[i], 32);
            qk1[i] = __shfl_xor(pk1[i], 32);
        }

        // ---- PV: oacc[d4] += V^T(32x16) * P(16x32); P B-frag k = ks*16+hi*8+j
        const char* vsb = (const char*)Vs[cur];
        #pragma unroll
        for (int ks = 0; ks < 4; ks++) {
            const int i0 = (ks & 1) * 4;
            union { u32 w[4]; bf16x8 v; } pf;
            if (ks & 2) {
                pf.w[0] = hi ? qk1[i0 + 2] : pk1[i0 + 0];
                pf.w[1] = hi ? qk1[i0 + 3] : pk1[i0 + 1];
                pf.w[2] = hi ? pk1[i0 + 2] : qk1[i0 + 0];
                pf.w[3] = hi ? pk1[i0 + 3] : qk1[i0 + 1];
            } else {
                pf.w[0] = hi ? qk0[i0 + 2] : pk0[i0 + 0];
                pf.w[1] = hi ? qk0[i0 + 3] : pk0[i0 + 1];
                pf.w[2] = hi ? pk0[i0 + 2] : qk0[i0 + 0];
                pf.w[3] = hi ? pk0[i0 + 3] : qk0[i0 + 1];
            }
            __builtin_amdgcn_s_setprio(1);
            #pragma unroll
            for (int d4 = 0; d4 < 4; d4++) {
                bf16x8 vf = *(const bf16x8*)(vsb + (d4 * 32 + l31) * 128
                                                 + ((ks * 32 + hi * 16) ^ swz));
                oacc[d4] = __builtin_amdgcn_mfma_f32_32x32x16_bf16(vf, pf.v, oacc[d4], 0, 0, 0);
            }
            __builtin_amdgcn_s_setprio(0);
        }
        __builtin_amdgcn_s_barrier();   // all reads of buf[cur] done before restage
    }

    // ---- epilogue: normalize; bounce through (dead) Ks for coalesced stores
    const float inv = 1.0f / l_run;
    u16* sl = (u16*)Ks + wave * (32 * 128);     // wave-private 8KB slice [32 q][128 d]
    #pragma unroll
    for (int d4 = 0; d4 < 4; d4++)
        #pragma unroll
        for (int rp = 0; rp < 8; rp++) {
            // d = d4*32 + 8*(rp>>1) + 4*hi + 2*(rp&1); byte offset = d*2
            int dbyte = d4 * 64 + 16 * (rp >> 1) + 8 * hi + 4 * (rp & 1);
            u32 w = (u32)f2b(oacc[d4][rp * 2] * inv)
                  | ((u32)f2b(oacc[d4][rp * 2 + 1] * inv) << 16);
            *(u32*)((char*)sl + l31 * 256 + (dbyte ^ swz)) = w;
        }
    #pragma unroll
    for (int j = 0; j < 8; j++) {
        int c = lane + j * 64;                  // 512 chunks: 32 q x 16 chunks
        int qL = c >> 4, dc = c & 15;
        uint4 v = *(uint4*)((char*)sl + qL * 256 + ((dc * 16) ^ ((qL & 7) << 4)));
        int qrow = qt * 128 + wave * 32 + qL;
        *(uint4*)(attn + (size_t)(b * S_ + qrow) * (HQ_ * D_) + hq * D_ + dc * 8) = v;
    }
}

// ---------------------------------------------------------------- launcher
extern "C" void kernel_launch(void* const* d_in, const int* in_sizes, int n_in,
                              void* d_out, int out_size, void* d_ws, size_t ws_size,
                              hipStream_t stream) {
    const float* hidden = (const float*)d_in[0];
    const float* cosb   = (const float*)d_in[1];
    const float* sinb   = (const float*)d_in[2];
    const float* qkvw   = (const float*)d_in[3];
    const float* nw     = (const float*)d_in[4];
    const float* ow     = (const float*)d_in[5];
    float* out = (float*)d_out;

    const size_t M  = (size_t)B_ * S_;             // 4096
    char* ws = (char*)d_ws;
    size_t off = 0;
    u16*   hb    = (u16*)(ws + off); off += M * HID * 2;                     // 16 MB (reused as attn)
    u16*   wqkvb = (u16*)(ws + off); off += (size_t)NQKV * HID * 2;          // 12 MB
    u16*   wob   = (u16*)(ws + off); off += (size_t)HID * (HQ_ * D_) * 2;    // 8 MB
    float* qkv   = (float*)(ws + off); off += M * NQKV * 4;                  // 48 MB
    u16*   qb2   = (u16*)(ws + off); off += (size_t)B_ * HQ_  * S_ * D_ * 2; // 16 MB
    u16*   kb2   = (u16*)(ws + off); off += (size_t)B_ * HKV_ * S_ * D_ * 2; // 4 MB
    u16*   vb2   = (u16*)(ws + off); off += (size_t)B_ * HKV_ * S_ * D_ * 2; // 4 MB
    u16*   vtb   = (u16*)(ws + off); off += (size_t)B_ * HKV_ * S_ * D_ * 2; // 4 MB
    u16*   attn  = hb;

    {
        int n4 = (int)(M * HID / 4);
        cvt_f32_bf16<<<(n4 + 255) / 256, 256, 0, stream>>>(hidden, hb, n4);
    }
    {
        int n4 = NQKV * HID / 4;
        cvt_f32_bf16<<<(n4 + 255) / 256, 256, 0, stream>>>(qkvw, wqkvb, n4);
    }
    {
        int n4 = HID * (HQ_ * D_) / 4;
        cvt_f32_bf16<<<(n4 + 255) / 256, 256, 0, stream>>>(ow, wob, n4);
    }

    gemm_bt_bf16<<<dim3(M / 128, NQKV / 128), 256, 0, stream>>>(hb, wqkvb, qkv,
                                                                (int)M, NQKV, HID);

    rope_norm_split<<<(int)M, 256, 0, stream>>>(qkv, cosb, sinb, nw, qb2, kb2, vb2);

    transpose_v<<<dim3(S_ / 64, D_ / 64, B_ * HKV_), 256, 0, stream>>>(vb2, vtb);

    attn_fwd3<<<dim3(16, B_ * HQ_), 256, 0, stream>>>(qb2, kb2, vtb, attn);

    gemm_bt_bf16<<<dim3(M / 128, HID / 128), 256, 0, stream>>>(attn, wob, out,
                                                               (int)M, HID, HQ_ * D_);
}

// Round 4
// 232.865 us; speedup vs baseline: 3.0472x; 1.0361x over previous
//
#include <hip/hip_runtime.h>
#include <hip/hip_bf16.h>

typedef __bf16 bf16_t;
typedef bf16_t bf16x8 __attribute__((ext_vector_type(8)));
typedef float f32x4 __attribute__((ext_vector_type(4)));
typedef float f32x16 __attribute__((ext_vector_type(16)));
typedef unsigned short u16;
typedef unsigned int u32;

#define B_    2
#define S_    2048
#define HID   2048
#define NQKV  3072          // (16 + 2*4) * 128
#define HQ_   16
#define HKV_  4
#define D_    128
// D^-0.5 * log2(e): folded into Q so softmax runs in exp2 domain
#define QSCALE_ 0.12751879526600565f

__device__ __forceinline__ u16 f2b(float f) {
    __hip_bfloat16 h = __float2bfloat16(f);
    return *reinterpret_cast<u16*>(&h);
}

// ---------------------------------------------------------------- f32 -> bf16
__global__ __launch_bounds__(256) void cvt_f32_bf16(const float* __restrict__ in,
                                                    u16* __restrict__ out, int n4) {
    int i = blockIdx.x * 256 + threadIdx.x;
    if (i >= n4) return;
    float4 v = reinterpret_cast<const float4*>(in)[i];
    ushort4 o;
    o.x = f2b(v.x); o.y = f2b(v.y); o.z = f2b(v.z); o.w = f2b(v.w);
    reinterpret_cast<ushort4*>(out)[i] = o;
}

// ---------------------------------------------------------------- GEMM 256x256, BK=64, 8 waves (2Mx4N)
// Deep pipeline: 4 quadrant-phases per K-tile, per-phase {ds_read || stage ||
// bar || 16 MFMA || bar}; counted vmcnt via issue-before-wait (never 0 in loop).
// LDS 128KB dbuf, XOR swizzle (byte ^= (row&7)<<4) on stage-src + read side.
// A: MxK row-major, B: NxK row-major (B^T), C: MxN f32.
__global__ __launch_bounds__(512, 1) void gemm256_bt(const u16* __restrict__ A,
                                                     const u16* __restrict__ Bm,
                                                     float* __restrict__ C,
                                                     int M, int N, int K) {
    extern __shared__ __align__(16) char smem[];
    u16* Asm = (u16*)smem;                 // [2][256*64]
    u16* Bsm = (u16*)smem + 32768;         // [2][256*64]

    const int tid  = threadIdx.x;
    const int lane = tid & 63;
    const int wid  = tid >> 6;
    const int wr = wid >> 2, wc = wid & 3;          // wave -> (128M x 64N) tile
    const int lrow = lane & 15, lgrp = lane >> 4;
    const int swz  = (lrow & 7) << 4;
    const int m0 = blockIdx.x * 256, n0 = blockIdx.y * 256;

    // staging geometry: chunk c = 1024*h + tid + 512*l; row = c>>3 (both loads
    // share (row&7) and slot), so one src column offset serves all stages.
    const int stRow = tid >> 3;                               // 0..63
    const int stCol = ((((tid & 7) * 16) ^ ((stRow & 7) << 4)) >> 1);

    const u16* aBase = A  + (size_t)(m0 + stRow) * K + stCol;
    const u16* bBase = Bm + (size_t)(n0 + stRow) * K + stCol;

    auto glds = [&](const u16* g, u16* l) {
        __builtin_amdgcn_global_load_lds(
            (const __attribute__((address_space(1))) void*)g,
            (__attribute__((address_space(3))) void*)l, 16, 0, 0);
    };
    auto stageA = [&](int buf, int h, int k0) {
        const u16* g = aBase + (size_t)(128 * h) * K + k0;
        u16* d = Asm + buf * 16384 + (1024 * h + tid) * 8;
        glds(g, d);
        glds(g + (size_t)64 * K, d + 512 * 8);
    };
    auto stageB = [&](int buf, int h, int k0) {
        const u16* g = bBase + (size_t)(128 * h) * K + k0;
        u16* d = Bsm + buf * 16384 + (1024 * h + tid) * 8;
        glds(g, d);
        glds(g + (size_t)64 * K, d + 512 * 8);
    };

    f32x4 acc[8][4] = {};
    const int KT = K >> 6;

    // prologue: stage tile 0 fully (8 loads in flight)
    stageA(0, 0, 0); stageA(0, 1, 0); stageB(0, 0, 0); stageB(0, 1, 0);

    for (int x = 0; x < KT; ++x) {
        const int cur = x & 1;
        const int kn  = (x + 1) << 6;
        const bool pf = (x + 1 < KT);
        const char* aT = (const char*)(Asm + cur * 16384);
        const char* bT = (const char*)(Bsm + cur * 16384);

        auto ldA = [&](int mi, int ks) -> bf16x8 {
            int row = wr * 128 + mi * 16 + lrow;
            return *(const bf16x8*)(aT + row * 128 + ((ks * 64 + lgrp * 16) ^ swz));
        };
        auto ldB = [&](int ni, int ks) -> bf16x8 {
            int row = wc * 64 + ni * 16 + lrow;
            return *(const bf16x8*)(bT + row * 128 + ((ks * 64 + lgrp * 16) ^ swz));
        };

        bf16x8 afr[4][2], bfr[2][2];

        // ---- phase 1: quadrant (qm0, qn0-1); stage A-half0(next); wait tile x
        if (pf) {
            stageA(cur ^ 1, 0, kn);
            asm volatile("s_waitcnt vmcnt(2)" ::: "memory");
        } else {
            asm volatile("s_waitcnt vmcnt(0)" ::: "memory");
        }
        __builtin_amdgcn_s_barrier();
        #pragma unroll
        for (int mi = 0; mi < 4; ++mi) { afr[mi][0] = ldA(mi, 0); afr[mi][1] = ldA(mi, 1); }
        #pragma unroll
        for (int ni = 0; ni < 2; ++ni) { bfr[ni][0] = ldB(ni, 0); bfr[ni][1] = ldB(ni, 1); }
        __builtin_amdgcn_s_setprio(1);
        #pragma unroll
        for (int mi = 0; mi < 4; ++mi)
            #pragma unroll
            for (int ni = 0; ni < 2; ++ni) {
                acc[mi][ni] = __builtin_amdgcn_mfma_f32_16x16x32_bf16(afr[mi][0], bfr[ni][0], acc[mi][ni], 0, 0, 0);
                acc[mi][ni] = __builtin_amdgcn_mfma_f32_16x16x32_bf16(afr[mi][1], bfr[ni][1], acc[mi][ni], 0, 0, 0);
            }
        __builtin_amdgcn_s_setprio(0);
        __builtin_amdgcn_s_barrier();

        // ---- phase 2: (qm0, qn2-3); stage A-half1(next); reuse afr
        #pragma unroll
        for (int ni = 0; ni < 2; ++ni) { bfr[ni][0] = ldB(ni + 2, 0); bfr[ni][1] = ldB(ni + 2, 1); }
        if (pf) stageA(cur ^ 1, 1, kn);
        __builtin_amdgcn_s_barrier();
        __builtin_amdgcn_s_setprio(1);
        #pragma unroll
        for (int mi = 0; mi < 4; ++mi)
            #pragma unroll
            for (int ni = 0; ni < 2; ++ni) {
                acc[mi][ni + 2] = __builtin_amdgcn_mfma_f32_16x16x32_bf16(afr[mi][0], bfr[ni][0], acc[mi][ni + 2], 0, 0, 0);
                acc[mi][ni + 2] = __builtin_amdgcn_mfma_f32_16x16x32_bf16(afr[mi][1], bfr[ni][1], acc[mi][ni + 2], 0, 0, 0);
            }
        __builtin_amdgcn_s_setprio(0);
        __builtin_amdgcn_s_barrier();

        // ---- phase 3: (qm1, qn2-3); stage B-half0(next); reuse bfr
        #pragma unroll
        for (int mi = 0; mi < 4; ++mi) { afr[mi][0] = ldA(mi + 4, 0); afr[mi][1] = ldA(mi + 4, 1); }
        if (pf) stageB(cur ^ 1, 0, kn);
        __builtin_amdgcn_s_barrier();
        __builtin_amdgcn_s_setprio(1);
        #pragma unroll
        for (int mi = 0; mi < 4; ++mi)
            #pragma unroll
            for (int ni = 0; ni < 2; ++ni) {
                acc[mi + 4][ni + 2] = __builtin_amdgcn_mfma_f32_16x16x32_bf16(afr[mi][0], bfr[ni][0], acc[mi + 4][ni + 2], 0, 0, 0);
                acc[mi + 4][ni + 2] = __builtin_amdgcn_mfma_f32_16x16x32_bf16(afr[mi][1], bfr[ni][1], acc[mi + 4][ni + 2], 0, 0, 0);
            }
        __builtin_amdgcn_s_setprio(0);
        __builtin_amdgcn_s_barrier();

        // ---- phase 4: (qm1, qn0-1); stage B-half1(next); reuse afr
        #pragma unroll
        for (int ni = 0; ni < 2; ++ni) { bfr[ni][0] = ldB(ni, 0); bfr[ni][1] = ldB(ni, 1); }
        if (pf) stageB(cur ^ 1, 1, kn);
        __builtin_amdgcn_s_barrier();
        __builtin_amdgcn_s_setprio(1);
        #pragma unroll
        for (int mi = 0; mi < 4; ++mi)
            #pragma unroll
            for (int ni = 0; ni < 2; ++ni) {
                acc[mi + 4][ni] = __builtin_amdgcn_mfma_f32_16x16x32_bf16(afr[mi][0], bfr[ni][0], acc[mi + 4][ni], 0, 0, 0);
                acc[mi + 4][ni] = __builtin_amdgcn_mfma_f32_16x16x32_bf16(afr[mi][1], bfr[ni][1], acc[mi + 4][ni], 0, 0, 0);
            }
        __builtin_amdgcn_s_setprio(0);
        __builtin_amdgcn_s_barrier();
    }

    // ---- epilogue: C write (f32)
    #pragma unroll
    for (int mi = 0; mi < 8; ++mi)
        #pragma unroll
        for (int ni = 0; ni < 4; ++ni) {
            int r = m0 + wr * 128 + mi * 16 + lgrp * 4;
            int c = n0 + wc * 64 + ni * 16 + lrow;
            float* p = C + (size_t)r * N + c;
            #pragma unroll
            for (int i = 0; i < 4; ++i) p[(size_t)i * N] = acc[mi][ni][i];
        }
}

// ---------------------------------------------------------------- RoPE (interleaved) + RMSNorm + split/relayout
// Q additionally pre-scaled by D^-0.5 * log2(e) (softmax runs in exp2 domain).
__global__ __launch_bounds__(256) void rope_norm_split(const float* __restrict__ qkv,
                                                       const float* __restrict__ cosb,
                                                       const float* __restrict__ sinb,
                                                       const float* __restrict__ nw,
                                                       u16* __restrict__ qb,
                                                       u16* __restrict__ kb,
                                                       u16* __restrict__ vb) {
    const int row  = blockIdx.x;          // b*S + s
    const int b    = row >> 11;
    const int s    = row & 2047;
    const int wave = threadIdx.x >> 6;
    const int lane = threadIdx.x & 63;
    const float* base = qkv + (size_t)row * NQKV;

    const float c0 = cosb[s * 128 + lane];
    const float c1 = cosb[s * 128 + 64 + lane];
    const float s0 = sinb[s * 128 + lane];
    const float s1 = sinb[s * 128 + 64 + lane];
    const float w0 = nw[2 * lane];
    const float w1 = nw[2 * lane + 1];

    for (int h = wave; h < HQ_ + HKV_; h += 4) {
        float2 x = *(const float2*)(base + h * 128 + 2 * lane);
        float y0 = x.x * c0 - x.y * s0;
        float y1 = x.y * c1 + x.x * s1;
        float ss = y0 * y0 + y1 * y1;
        #pragma unroll
        for (int off = 32; off; off >>= 1) ss += __shfl_xor(ss, off);
        float r = rsqrtf(ss * (1.0f / 128.0f) + 1e-6f);
        float o0 = y0 * r * w0, o1 = y1 * r * w1;
        if (h < HQ_) {
            u32 pack = (u32)f2b(o0 * QSCALE_) | ((u32)f2b(o1 * QSCALE_) << 16);
            *(u32*)(qb + ((size_t)(b * HQ_ + h) * S_ + s) * D_ + 2 * lane) = pack;
        } else {
            u32 pack = (u32)f2b(o0) | ((u32)f2b(o1) << 16);
            *(u32*)(kb + ((size_t)(b * HKV_ + (h - HQ_)) * S_ + s) * D_ + 2 * lane) = pack;
        }
    }
    {
        int h = wave;
        float2 x = *(const float2*)(base + (HQ_ + HKV_) * 128 + h * 128 + 2 * lane);
        u32 pack = (u32)f2b(x.x) | ((u32)f2b(x.y) << 16);
        *(u32*)(vb + ((size_t)(b * HKV_ + h) * S_ + s) * D_ + 2 * lane) = pack;
    }
}

// ---------------------------------------------------------------- V transpose: (B,HKV,S,D) -> (B,HKV,D,S)
__global__ __launch_bounds__(256) void transpose_v(const u16* __restrict__ vb,
                                                   u16* __restrict__ vtb) {
    __shared__ u16 t[64][72];
    const int s0 = blockIdx.x * 64, d0 = blockIdx.y * 64, bh = blockIdx.z;
    const u16* src = vb  + (size_t)bh * S_ * D_;
    u16*       dst = vtb + (size_t)bh * D_ * S_;
    const int tid = threadIdx.x;

    {
        int r = tid >> 3, c8 = (tid & 7) * 8;
        #pragma unroll
        for (int p = 0; p < 2; p++) {
            int rr = r + p * 32;
            *(uint4*)&t[rr][c8] = *(const uint4*)(src + (size_t)(s0 + rr) * D_ + d0 + c8);
        }
    }
    __syncthreads();
    {
        int dd = tid & 63;
        int sb = (tid >> 6) * 8;
        #pragma unroll
        for (int p = 0; p < 2; p++) {
            int ss8 = sb + p * 32;
            union { u16 u[8]; uint4 v; } pk;
            #pragma unroll
            for (int j = 0; j < 8; j++) pk.u[j] = t[ss8 + j][dd];
            *(uint4*)(dst + (size_t)(d0 + dd) * S_ + s0 + ss8) = pk.v;
        }
    }
}

// ---------------------------------------------------------------- causal GQA flash attention v3
// Swapped-QK^T structure: 4 waves x 32 q-rows (QBLK=128), KVBLK=64, mfma_32x32x16.
__global__ __launch_bounds__(256, 2) void attn_fwd3(const u16* __restrict__ qb,
                                                    const u16* __restrict__ kb,
                                                    const u16* __restrict__ vtb,
                                                    u16* __restrict__ attn) {
    __shared__ __align__(16) u16 Ks[2][64 * 128];   // 32KB (reused as O bounce)
    __shared__ __align__(16) u16 Vs[2][128 * 64];   // 32KB

    const int bh  = blockIdx.y;
    const int qt  = (bh < 16) ? (15 - (int)blockIdx.x) : (int)blockIdx.x;
    const int b   = bh >> 4, hq = bh & 15, hkv = hq >> 2;
    const int tid = threadIdx.x;
    const int wave = tid >> 6, lane = tid & 63;
    const int l31 = lane & 31, hi = lane >> 5;
    const int swz = (l31 & 7) << 4;

    const u16* Q  = qb  + (size_t)(b * HQ_  + hq ) * S_ * D_;
    const u16* Kp = kb  + (size_t)(b * HKV_ + hkv) * S_ * D_;
    const u16* Vt = vtb + (size_t)(b * HKV_ + hkv) * D_ * S_;
    const int q0w = qt * 128 + wave * 32;
    const int qg  = q0w + l31;            // this lane's q row

    int kSrc[4], vSrc[4], cLds[4];
    #pragma unroll
    for (int p = 0; p < 4; p++) {
        int c = tid + p * 256;
        int kr = c >> 4, kc = ((c & 15) * 16) ^ ((kr & 7) << 4);
        kSrc[p] = kr * D_ + (kc >> 1);
        int vr = c >> 3, vc = ((c & 7) * 16) ^ ((vr & 7) << 4);
        vSrc[p] = vr * S_ + (vc >> 1);
        cLds[p] = c * 16;
    }

    auto STAGE = [&](int buf, int kv0s) {
        const u16* kbase = Kp + (size_t)kv0s * D_;
        const u16* vbase = Vt + kv0s;
        #pragma unroll
        for (int p = 0; p < 4; p++)
            __builtin_amdgcn_global_load_lds(
                (const __attribute__((address_space(1))) void*)(kbase + kSrc[p]),
                (__attribute__((address_space(3))) void*)((char*)Ks[buf] + cLds[p]), 16, 0, 0);
        #pragma unroll
        for (int p = 0; p < 4; p++)
            __builtin_amdgcn_global_load_lds(
                (const __attribute__((address_space(1))) void*)(vbase + vSrc[p]),
                (__attribute__((address_space(3))) void*)((char*)Vs[buf] + cLds[p]), 16, 0, 0);
    };

    bf16x8 qf[8];
    #pragma unroll
    for (int ds = 0; ds < 8; ds++)
        qf[ds] = *(const bf16x8*)(Q + (size_t)qg * D_ + ds * 16 + hi * 8);

    float m_run = -1e30f, l_run = 0.f;
    f32x16 oacc[4] = {};

    const int nkt = 2 * qt + 2;
    STAGE(0, 0);

    for (int kt = 0; kt < nkt; kt++) {
        const int cur = kt & 1;
        const int kv0 = kt * 64;
        if (kt + 1 < nkt) {
            STAGE(cur ^ 1, kv0 + 64);
            asm volatile("s_waitcnt vmcnt(8)" ::: "memory");
        } else {
            asm volatile("s_waitcnt vmcnt(0)" ::: "memory");
        }
        __builtin_amdgcn_s_barrier();

        const char* ksb = (const char*)Ks[cur];
        f32x16 sc[2] = {};
        __builtin_amdgcn_s_setprio(1);
        #pragma unroll
        for (int blk = 0; blk < 2; blk++) {
            const char* rowb = ksb + (blk * 32 + l31) * 256;
            #pragma unroll
            for (int ds = 0; ds < 8; ds++) {
                bf16x8 kf = *(const bf16x8*)(rowb + ((ds * 32 + hi * 16) ^ swz));
                sc[blk] = __builtin_amdgcn_mfma_f32_32x32x16_bf16(kf, qf[ds], sc[blk], 0, 0, 0);
            }
        }
        __builtin_amdgcn_s_setprio(0);

        if (kv0 + 63 > q0w) {
            #pragma unroll
            for (int blk = 0; blk < 2; blk++)
                #pragma unroll
                for (int r = 0; r < 16; r++) {
                    int kvg = kv0 + blk * 32 + (r & 3) + 8 * (r >> 2) + 4 * hi;
                    if (kvg > qg) sc[blk][r] = -1e30f;
                }
        }

        float t16[16];
        #pragma unroll
        for (int r = 0; r < 16; r++) t16[r] = fmaxf(sc[0][r], sc[1][r]);
        #pragma unroll
        for (int r = 0; r < 8; r++) t16[r] = fmaxf(t16[r], t16[r + 8]);
        #pragma unroll
        for (int r = 0; r < 4; r++) t16[r] = fmaxf(t16[r], t16[r + 4]);
        float mt = fmaxf(fmaxf(t16[0], t16[1]), fmaxf(t16[2], t16[3]));
        mt = fmaxf(mt, __shfl_xor(mt, 32));

        bool noDefer = !__all(mt <= m_run + 8.0f);
        float mnew = m_run;
        if (noDefer) {
            mnew = fmaxf(m_run, mt);
            float alpha = __builtin_amdgcn_exp2f(m_run - mnew);
            l_run *= alpha;
            #pragma unroll
            for (int d4 = 0; d4 < 4; d4++)
                #pragma unroll
                for (int r = 0; r < 16; r++) oacc[d4][r] *= alpha;
            m_run = mnew;
        }

        float la = 0.f;
        u32 pk0[8], pk1[8];
        #pragma unroll
        for (int g = 0; g < 4; g++)
            #pragma unroll
            for (int e = 0; e < 2; e++) {
                float a0 = __builtin_amdgcn_exp2f(sc[0][g * 4 + 2 * e]     - mnew);
                float b0 = __builtin_amdgcn_exp2f(sc[0][g * 4 + 2 * e + 1] - mnew);
                float a1 = __builtin_amdgcn_exp2f(sc[1][g * 4 + 2 * e]     - mnew);
                float b1 = __builtin_amdgcn_exp2f(sc[1][g * 4 + 2 * e + 1] - mnew);
                la += (a0 + b0) + (a1 + b1);
                pk0[g * 2 + e] = (u32)f2b(a0) | ((u32)f2b(b0) << 16);
                pk1[g * 2 + e] = (u32)f2b(a1) | ((u32)f2b(b1) << 16);
            }
        la += __shfl_xor(la, 32);
        l_run += la;

        u32 qk0[8], qk1[8];
        #pragma unroll
        for (int i = 0; i < 8; i++) {
            qk0[i] = __shfl_xor(pk0[i], 32);
            qk1[i] = __shfl_xor(pk1[i], 32);
        }

        const char* vsb = (const char*)Vs[cur];
        #pragma unroll
        for (int ks = 0; ks < 4; ks++) {
            const int i0 = (ks & 1) * 4;
            union { u32 w[4]; bf16x8 v; } pf;
            if (ks & 2) {
                pf.w[0] = hi ? qk1[i0 + 2] : pk1[i0 + 0];
                pf.w[1] = hi ? qk1[i0 + 3] : pk1[i0 + 1];
                pf.w[2] = hi ? pk1[i0 + 2] : qk1[i0 + 0];
                pf.w[3] = hi ? pk1[i0 + 3] : qk1[i0 + 1];
            } else {
                pf.w[0] = hi ? qk0[i0 + 2] : pk0[i0 + 0];
                pf.w[1] = hi ? qk0[i0 + 3] : pk0[i0 + 1];
                pf.w[2] = hi ? pk0[i0 + 2] : qk0[i0 + 0];
                pf.w[3] = hi ? pk0[i0 + 3] : qk0[i0 + 1];
            }
            __builtin_amdgcn_s_setprio(1);
            #pragma unroll
            for (int d4 = 0; d4 < 4; d4++) {
                bf16x8 vf = *(const bf16x8*)(vsb + (d4 * 32 + l31) * 128
                                                 + ((ks * 32 + hi * 16) ^ swz));
                oacc[d4] = __builtin_amdgcn_mfma_f32_32x32x16_bf16(vf, pf.v, oacc[d4], 0, 0, 0);
            }
            __builtin_amdgcn_s_setprio(0);
        }
        __builtin_amdgcn_s_barrier();
    }

    const float inv = 1.0f / l_run;
    u16* sl = (u16*)Ks + wave * (32 * 128);
    #pragma unroll
    for (int d4 = 0; d4 < 4; d4++)
        #pragma unroll
        for (int rp = 0; rp < 8; rp++) {
            int dbyte = d4 * 64 + 16 * (rp >> 1) + 8 * hi + 4 * (rp & 1);
            u32 w = (u32)f2b(oacc[d4][rp * 2] * inv)
                  | ((u32)f2b(oacc[d4][rp * 2 + 1] * inv) << 16);
            *(u32*)((char*)sl + l31 * 256 + (dbyte ^ swz)) = w;
        }
    #pragma unroll
    for (int j = 0; j < 8; j++) {
        int c = lane + j * 64;
        int qL = c >> 4, dc = c & 15;
        uint4 v = *(uint4*)((char*)sl + qL * 256 + ((dc * 16) ^ ((qL & 7) << 4)));
        int qrow = qt * 128 + wave * 32 + qL;
        *(uint4*)(attn + (size_t)(b * S_ + qrow) * (HQ_ * D_) + hq * D_ + dc * 8) = v;
    }
}

// ---------------------------------------------------------------- launcher
extern "C" void kernel_launch(void* const* d_in, const int* in_sizes, int n_in,
                              void* d_out, int out_size, void* d_ws, size_t ws_size,
                              hipStream_t stream) {
    const float* hidden = (const float*)d_in[0];
    const float* cosb   = (const float*)d_in[1];
    const float* sinb   = (const float*)d_in[2];
    const float* qkvw   = (const float*)d_in[3];
    const float* nw     = (const float*)d_in[4];
    const float* ow     = (const float*)d_in[5];
    float* out = (float*)d_out;

    const size_t M  = (size_t)B_ * S_;             // 4096
    char* ws = (char*)d_ws;
    size_t off = 0;
    u16*   hb    = (u16*)(ws + off); off += M * HID * 2;                     // 16 MB (reused as attn)
    u16*   wqkvb = (u16*)(ws + off); off += (size_t)NQKV * HID * 2;          // 12 MB
    u16*   wob   = (u16*)(ws + off); off += (size_t)HID * (HQ_ * D_) * 2;    // 8 MB
    float* qkv   = (float*)(ws + off); off += M * NQKV * 4;                  // 48 MB
    u16*   qb2   = (u16*)(ws + off); off += (size_t)B_ * HQ_  * S_ * D_ * 2; // 16 MB
    u16*   kb2   = (u16*)(ws + off); off += (size_t)B_ * HKV_ * S_ * D_ * 2; // 4 MB
    u16*   vb2   = (u16*)(ws + off); off += (size_t)B_ * HKV_ * S_ * D_ * 2; // 4 MB
    u16*   vtb   = (u16*)(ws + off); off += (size_t)B_ * HKV_ * S_ * D_ * 2; // 4 MB
    u16*   attn  = hb;

    {
        int n4 = (int)(M * HID / 4);
        cvt_f32_bf16<<<(n4 + 255) / 256, 256, 0, stream>>>(hidden, hb, n4);
    }
    {
        int n4 = NQKV * HID / 4;
        cvt_f32_bf16<<<(n4 + 255) / 256, 256, 0, stream>>>(qkvw, wqkvb, n4);
    }
    {
        int n4 = HID * (HQ_ * D_) / 4;
        cvt_f32_bf16<<<(n4 + 255) / 256, 256, 0, stream>>>(ow, wob, n4);
    }

    const int smemSz = 131072;
    hipFuncSetAttribute(reinterpret_cast<const void*>(gemm256_bt),
                        hipFuncAttributeMaxDynamicSharedMemorySize, smemSz);

    gemm256_bt<<<dim3(M / 256, NQKV / 256), 512, smemSz, stream>>>(hb, wqkvb, qkv,
                                                                   (int)M, NQKV, HID);

    rope_norm_split<<<(int)M, 256, 0, stream>>>(qkv, cosb, sinb, nw, qb2, kb2, vb2);

    transpose_v<<<dim3(S_ / 64, D_ / 64, B_ * HKV_), 256, 0, stream>>>(vb2, vtb);

    attn_fwd3<<<dim3(16, B_ * HQ_), 256, 0, stream>>>(qb2, kb2, vtb, attn);

    gemm256_bt<<<dim3(M / 256, HID / 256), 512, smemSz, stream>>>(attn, wob, out,
                                                                  (int)M, HID, HQ_ * D_);
}